// Round 13
// baseline (212.319 us; speedup 1.0000x reference)
//
#include <hip/hip_runtime.h>
#include <cstdint>
#include <cstddef>

// Problem: x += ssm_scan(rmsnorm(x,s1)); out = x + gelu(rmsnorm(x,s2)@w1+b1)@w2+b2
// B=4 L=2048 D=1024 N=16 DFF=4096, f32 in/out. bf16 MFMA GEMMs.

#define BATCH 4
#define SEQLEN 2048
#define DMODEL 1024
#define NSTATE 16
#define DFF 4096
#define NCH 32     // chunks over L
#define LCH 64     // SEQLEN / NCH

typedef unsigned short ushort_t;
typedef __attribute__((ext_vector_type(8))) short short8;
typedef __attribute__((ext_vector_type(4))) float f32x4;

__device__ __forceinline__ ushort_t f2bf(float f) {
  uint32_t u = __builtin_bit_cast(uint32_t, f);
  uint32_t r = (u + 0x7FFFu + ((u >> 16) & 1u)) >> 16;
  return (ushort_t)r;
}

// ---------------- coefficient precompute ----------------
__global__ void coef_kernel(const float* __restrict__ A_ssm, const float* __restrict__ B_ssm,
                            const float* __restrict__ C_ssm,
                            float* __restrict__ dA_t, float* __restrict__ dBz_t,
                            float* __restrict__ dAc_t, float* __restrict__ Ct) {
  int d = blockIdx.x * 256 + threadIdx.x;
  if (d >= DMODEL) return;
  const float l0 = -6.907755278982137f;       // log(0.001)
  const float ld = 0.30701134573253947f;      // log(100)/15
  for (int n = 0; n < NSTATE; n++) {
    float dt = expf(l0 + (float)n * ld);
    float a  = A_ssm[d * NSTATE + n];
    float ea = expf(a);
    float da = expf(-ea * dt);
    float dbz = B_ssm[d * NSTATE + n] * (1.f - da) / ea;
    float dac = expf(-ea * dt * (float)LCH);
    dA_t [n * DMODEL + d] = da;
    dBz_t[n * DMODEL + d] = dbz;
    dAc_t[n * DMODEL + d] = dac;
    Ct   [n * DMODEL + d] = C_ssm[d * NSTATE + n];
  }
}

// ---------------- transpose f32 [R][C] -> bf16 [C][R] ----------------
__global__ void transpose_to_bf16(const float* __restrict__ src, ushort_t* __restrict__ dst,
                                  int R, int C) {
  __shared__ float tile[32][33];
  int bx = blockIdx.x * 32, by = blockIdx.y * 32;
  int tx = threadIdx.x, ty = threadIdx.y;
  #pragma unroll
  for (int i = 0; i < 4; i++) {
    int r = by + ty + i * 8;
    tile[ty + i * 8][tx] = src[(size_t)r * C + bx + tx];
  }
  __syncthreads();
  #pragma unroll
  for (int i = 0; i < 4; i++) {
    int c = bx + ty + i * 8;
    dst[(size_t)c * R + by + tx] = f2bf(tile[tx][ty + i * 8]);
  }
}

// ---------------- rmsnorm pass 1: rrms per row ----------------
__global__ void rms1_kernel(const float* __restrict__ x, float* __restrict__ rrms) {
  int row = blockIdx.x * 4 + (threadIdx.x >> 6);
  int lane = threadIdx.x & 63;
  const float4* p = (const float4*)(x + (size_t)row * DMODEL);
  float s = 0.f;
  #pragma unroll
  for (int w = 0; w < 4; w++) {
    float4 v = p[w * 64 + lane];
    s += v.x * v.x + v.y * v.y + v.z * v.z + v.w * v.w;
  }
  #pragma unroll
  for (int off = 32; off; off >>= 1) s += __shfl_xor(s, off, 64);
  if (lane == 0) rrms[row] = rsqrtf(s * (1.f / DMODEL) + 1e-6f);
}

// ---------------- scan pass1: per-chunk local final states ----------------
__global__ void scan_pass1(const float* __restrict__ x, const float* __restrict__ rrms,
                           const float* __restrict__ scale1,
                           const float* __restrict__ dA_t, const float* __restrict__ dBz_t,
                           float* __restrict__ s_fin) {
  int d = blockIdx.x * 256 + threadIdx.x;
  int b = blockIdx.y, c = blockIdx.z;
  float dA[NSTATE], dBz[NSTATE], s[NSTATE];
  #pragma unroll
  for (int n = 0; n < NSTATE; n++) {
    dA[n] = dA_t[n * DMODEL + d];
    dBz[n] = dBz_t[n * DMODEL + d];
    s[n] = 0.f;
  }
  float sc1 = scale1[d];
  const float* xp = x + ((size_t)b * SEQLEN + (size_t)c * LCH) * DMODEL + d;
  const float* rp = rrms + b * SEQLEN + c * LCH;
  for (int t = 0; t < LCH; t++) {
    float u = xp[(size_t)t * DMODEL] * rp[t] * sc1;
    #pragma unroll
    for (int n = 0; n < NSTATE; n++) s[n] = fmaf(s[n], dA[n], u * dBz[n]);
  }
  #pragma unroll
  for (int n = 0; n < NSTATE; n++)
    s_fin[(((size_t)n * BATCH + b) * NCH + c) * DMODEL + d] = s[n];
}

// ---------------- scan pass2: serial chunk-carry combine ----------------
__global__ void scan_pass2(const float* __restrict__ s_fin, const float* __restrict__ dAc_t,
                           float* __restrict__ s_in) {
  int idx = blockIdx.x * 256 + threadIdx.x;  // BATCH*DMODEL*NSTATE = 65536
  int d = idx & (DMODEL - 1);
  int b = (idx >> 10) & (BATCH - 1);
  int n = idx >> 12;
  float dc = dAc_t[n * DMODEL + d];
  float s = 0.f;
  for (int c = 0; c < NCH; c++) {
    size_t o = (((size_t)n * BATCH + b) * NCH + c) * DMODEL + d;
    s_in[o] = s;
    s = s_fin[o] + dc * s;
  }
}

// ---------------- scan pass3: full scan with carry-in, write x2 = x + y + u*D ----------------
__global__ void scan_pass3(const float* __restrict__ x, const float* __restrict__ rrms,
                           const float* __restrict__ scale1,
                           const float* __restrict__ dA_t, const float* __restrict__ dBz_t,
                           const float* __restrict__ Ct, const float* __restrict__ Dv,
                           const float* __restrict__ s_in, float* __restrict__ out) {
  int d = blockIdx.x * 256 + threadIdx.x;
  int b = blockIdx.y, c = blockIdx.z;
  float dA[NSTATE], dBz[NSTATE], Cc[NSTATE], s[NSTATE];
  #pragma unroll
  for (int n = 0; n < NSTATE; n++) {
    dA[n] = dA_t[n * DMODEL + d];
    dBz[n] = dBz_t[n * DMODEL + d];
    Cc[n] = Ct[n * DMODEL + d];
    s[n] = s_in[(((size_t)n * BATCH + b) * NCH + c) * DMODEL + d];
  }
  float sc1 = scale1[d], Dd = Dv[d];
  const float* xp = x + ((size_t)b * SEQLEN + (size_t)c * LCH) * DMODEL + d;
  const float* rp = rrms + b * SEQLEN + c * LCH;
  float* op = out + ((size_t)b * SEQLEN + (size_t)c * LCH) * DMODEL + d;
  for (int t = 0; t < LCH; t++) {
    float xv = xp[(size_t)t * DMODEL];
    float u = xv * rp[t] * sc1;
    float y = 0.f;
    #pragma unroll
    for (int n = 0; n < NSTATE; n++) {
      s[n] = fmaf(s[n], dA[n], u * dBz[n]);
      y = fmaf(Cc[n], s[n], y);
    }
    op[(size_t)t * DMODEL] = xv + y + u * Dd;
  }
}

// ---------------- rmsnorm2: x2 -> bf16 normalized ----------------
__global__ void rms2_kernel(const float* __restrict__ x2, const float* __restrict__ scale2,
                            ushort_t* __restrict__ hb) {
  int row = blockIdx.x * 4 + (threadIdx.x >> 6);
  int lane = threadIdx.x & 63;
  const float4* p = (const float4*)(x2 + (size_t)row * DMODEL);
  float4 v[4];
  float s = 0.f;
  #pragma unroll
  for (int w = 0; w < 4; w++) {
    v[w] = p[w * 64 + lane];
    s += v[w].x * v[w].x + v[w].y * v[w].y + v[w].z * v[w].z + v[w].w * v[w].w;
  }
  #pragma unroll
  for (int off = 32; off; off >>= 1) s += __shfl_xor(s, off, 64);
  float r = rsqrtf(s * (1.f / DMODEL) + 1e-6f);
  const float4* sc = (const float4*)scale2;
  #pragma unroll
  for (int w = 0; w < 4; w++) {
    float4 scv = sc[w * 64 + lane];
    ushort4 u;
    u.x = f2bf(v[w].x * r * scv.x);
    u.y = f2bf(v[w].y * r * scv.y);
    u.z = f2bf(v[w].z * r * scv.z);
    u.w = f2bf(v[w].w * r * scv.w);
    *(ushort4*)(hb + (size_t)row * DMODEL + (size_t)(w * 64 + lane) * 4) = u;
  }
}

template <int N>
__device__ __forceinline__ void fence_vm() {
  asm volatile("s_waitcnt vmcnt(%0)" :: "n"(N) : "memory");
}

__device__ __forceinline__ void bar() { asm volatile("s_barrier" ::: "memory"); }

__device__ __forceinline__ void gl2lds16(const ushort_t* g, ushort_t* l) {
  __builtin_amdgcn_global_load_lds(
      (const __attribute__((address_space(1))) unsigned int*)g,
      (__attribute__((address_space(3))) unsigned int*)l, 16, 0, 0);
}

// ========== gemm1: faithful 8-phase template (m201 schedule) ==========
// 256x256, BK=64, 2 K-tiles/iter, 8 waves (2Mx4N), wave tile 128x64 (read:MFMA 0.375,
// LDS floor 2304cy < matrix 2483cy -> matrix-bound). LDS: A[2][256][64]@0, B[2][256][64]@32768.
// Per phase: {ds_reads (12/8/4/0); stage ONE half-tile (2 gl2lds); [vmcnt(4) @p3,p7 ONLY];
//            s_barrier; setprio; 16 MFMA (one quadrant x K=64); setprio; s_barrier}.
// Stage order (periodic): p0:B0(t+1) p1:B1(t+1) p2:A0(t+2) p3:A1(t+2) p4:B0(t+2)
//                         p5:B1(t+2) p6:A0(t+3) p7:A1(t+3).
// Audits: write-after-read — every staged half's last reader finished >=1 phase earlier
// (A halves last read p1, staged p2/p3; B halves last read p2, staged p4/p5; cross-iter
// halves 2+ phases). Landing — vmcnt(4)@p3 => stages<=p1 landed => tile t+1 complete
// before p4; vmcnt(4)@p7 => t+2 complete before next p0. Prologue: 6 halves + vmcnt(4).
// Last iter peeled: no t+2/t+3 stages, vmcnt(0)@p3.
#define RDA_(DST, BASE)                                                  \
  _Pragma("unroll") for (int m_ = 0; m_ < 4; ++m_) {                     \
    DST[0][m_] = *(const short8*)((BASE) + sw0 + m_ * 1024);             \
    DST[1][m_] = *(const short8*)((BASE) + sw1 + m_ * 1024);             \
  }
#define RDB_(DST, BASE, NP)                                              \
  _Pragma("unroll") for (int n_ = 0; n_ < 2; ++n_) {                     \
    DST[0][n_] = *(const short8*)((BASE) + sw0 + ((NP)*2 + n_) * 1024);  \
    DST[1][n_] = *(const short8*)((BASE) + sw1 + ((NP)*2 + n_) * 1024);  \
  }
#define MMAQ(S, NP, AF, BF)                                              \
  __builtin_amdgcn_s_setprio(1);                                         \
  _Pragma("unroll") for (int kk_ = 0; kk_ < 2; ++kk_)                    \
  _Pragma("unroll") for (int m_ = 0; m_ < 4; ++m_)                       \
  _Pragma("unroll") for (int n_ = 0; n_ < 2; ++n_)                       \
    acc[(S)*4 + m_][(NP)*2 + n_] = __builtin_amdgcn_mfma_f32_16x16x32_bf16( \
        AF[kk_][m_], BF[kk_][n_], acc[(S)*4 + m_][(NP)*2 + n_], 0, 0, 0);\
  __builtin_amdgcn_s_setprio(0);

template <int K>
__global__ __launch_bounds__(512, 2) void gemm8f(const ushort_t* __restrict__ A,
                                                 const ushort_t* __restrict__ B,
                                                 const float* __restrict__ bias,
                                                 ushort_t* __restrict__ outp,
                                                 int M, int N) {
  constexpr int NT = K / 64;
  constexpr int NITER = NT / 2;
  __shared__ __align__(16) ushort_t lds[65536];   // 128 KB

  const int tid = threadIdx.x;
  const int wave = tid >> 6, lane = tid & 63;
  const int wr = wave >> 2, wc = wave & 3;        // 2 x 4 waves

  const int nwg = gridDim.x, cpx = nwg >> 3, bid = blockIdx.x;
  const int wg = (bid & 7) * cpx + (bid >> 3);
  const int nbn = N / 256;
  const int m0 = (wg / nbn) * 256, n0 = (wg % nbn) * 256;

  // staging: rows tid>>3 within 64-row groups, chunk tid&7, BK=64 swizzle (src pre-swz)
  const int scol = 8 * ((tid & 7) ^ ((tid >> 3) & 7));
  const ushort_t* gA = A + (size_t)(m0 + (tid >> 3)) * K + scol;
  const ushort_t* gB = B + (size_t)(n0 + (tid >> 3)) * K + scol;
  const int wo = wave * 512;

  auto stgA = [&](int buf, int h, int t) {   // half h = rows h*128..+127 of A tile t
    ushort_t* d = lds + buf * 16384 + h * 8192 + wo;
    const ushort_t* s = gA + (size_t)(h * 128) * K + (size_t)t * 64;
    gl2lds16(s, d);
    gl2lds16(s + (size_t)64 * K, d + 4096);
  };
  auto stgB = [&](int buf, int h, int t) {
    ushort_t* d = lds + 32768 + buf * 16384 + h * 8192 + wo;
    const ushort_t* s = gB + (size_t)(h * 128) * K + (size_t)t * 64;
    gl2lds16(s, d);
    gl2lds16(s + (size_t)64 * K, d + 4096);
  };

  f32x4 acc[8][4] = {};

  // prologue: tile0 (buf0) all halves, tile1 (buf1) A halves; B(1) staged at p0/p1.
  stgA(0, 0, 0); stgA(0, 1, 0); stgB(0, 0, 0); stgB(0, 1, 0);
  stgA(1, 0, 1); stgA(1, 1, 1);
  fence_vm<4>(); bar();

  const int rl = lane & 15, c4 = lane >> 4;
  const int sw0 = (c4 ^ (rl & 7)) * 8;           // kk=0 swizzled col (BK=64 pattern)
  const int sw1 = ((4 | c4) ^ (rl & 7)) * 8;     // kk=1
  // loop-invariant read bases
  const ushort_t* aR00 = lds + (wr * 128 + 0 * 64 + rl) * 64;            // buf0, s0
  const ushort_t* aR01 = aR00 + 4096;                                    // buf0, s1
  const ushort_t* aR10 = aR00 + 16384;                                   // buf1, s0
  const ushort_t* aR11 = aR10 + 4096;                                    // buf1, s1
  const ushort_t* bR0  = lds + 32768 + (wc * 64 + rl) * 64;              // buf0
  const ushort_t* bR1  = bR0 + 16384;                                    // buf1

  short8 Af0[2][4], Af1[2][4], Bf01[2][2], Bf23[2][2];

  for (int i = 0; i < NITER - 1; ++i) {
    const int t1 = 2 * i + 1, t2 = 2 * i + 2, t3 = 2 * i + 3;
    // p0
    RDA_(Af0, aR00) RDB_(Bf01, bR0, 0) stgB(1, 0, t1);
    bar(); MMAQ(0, 0, Af0, Bf01) bar();
    // p1
    RDA_(Af1, aR01) stgB(1, 1, t1);
    bar(); MMAQ(1, 0, Af1, Bf01) bar();
    // p2
    RDB_(Bf23, bR0, 1) stgA(0, 0, t2);
    bar(); MMAQ(0, 1, Af0, Bf23) bar();
    // p3
    stgA(0, 1, t2); fence_vm<4>();
    bar(); MMAQ(1, 1, Af1, Bf23) bar();
    // p4
    RDA_(Af0, aR10) RDB_(Bf01, bR1, 0) stgB(0, 0, t2);
    bar(); MMAQ(0, 0, Af0, Bf01) bar();
    // p5
    RDA_(Af1, aR11) stgB(0, 1, t2);
    bar(); MMAQ(1, 0, Af1, Bf01) bar();
    // p6
    RDB_(Bf23, bR1, 1) stgA(1, 0, t3);
    bar(); MMAQ(0, 1, Af0, Bf23) bar();
    // p7
    stgA(1, 1, t3); fence_vm<4>();
    bar(); MMAQ(1, 1, Af1, Bf23) bar();
  }
  {   // peeled last iteration (tau = NT-2): only B(NT-1) stages remain
    RDA_(Af0, aR00) RDB_(Bf01, bR0, 0) stgB(1, 0, NT - 1);
    bar(); MMAQ(0, 0, Af0, Bf01) bar();
    RDA_(Af1, aR01) stgB(1, 1, NT - 1);
    bar(); MMAQ(1, 0, Af1, Bf01) bar();
    RDB_(Bf23, bR0, 1)
    bar(); MMAQ(0, 1, Af0, Bf23) bar();
    fence_vm<0>();
    bar(); MMAQ(1, 1, Af1, Bf23) bar();
    RDA_(Af0, aR10) RDB_(Bf01, bR1, 0)
    bar(); MMAQ(0, 0, Af0, Bf01) bar();
    RDA_(Af1, aR11)
    bar(); MMAQ(1, 0, Af1, Bf01) bar();
    RDB_(Bf23, bR1, 1)
    bar(); MMAQ(0, 1, Af0, Bf23) bar();
    bar(); MMAQ(1, 1, Af1, Bf23) bar();
  }

  // epilogue: gelu (sigmoid approx) -> bf16. rows: wr*128 + s*64 + m*16; cols: wc*64 + n*16.
  const int colb = n0 + wc * 64 + rl;
  const int rowb = m0 + wr * 128 + c4 * 4;
  #pragma unroll
  for (int n = 0; n < 4; n++) {
    int col = colb + n * 16;
    float bs = bias[col];
    #pragma unroll
    for (int mi = 0; mi < 8; mi++) {
      int row = rowb + (mi >> 2) * 64 + (mi & 3) * 16;
      #pragma unroll
      for (int j = 0; j < 4; j++) {
        float v = acc[mi][n][j] + bs;
        float g = v / (1.f + __expf(-1.702f * v));
        outp[(size_t)(row + j) * N + col] = f2bf(g);
      }
    }
  }
}

// ========== gemm2: r12 structure unchanged (256x128, BK=64, 3-slot, 16 waves) ==========
template <int K, int MODE>
__global__ __launch_bounds__(1024, 4) void gemm16v(const ushort_t* __restrict__ A,
                                                   const ushort_t* __restrict__ B,
                                                   const float* __restrict__ bias,
                                                   const float* __restrict__ resid,
                                                   void* __restrict__ outp,
                                                   int M, int N) {
  constexpr int TILEA = 16384;
  constexpr int SLOT  = TILEA + 8192;
  constexpr int NT = K / 64;
  __shared__ __align__(16) ushort_t lds[3 * SLOT];   // 144 KB

  const int tid = threadIdx.x;
  const int wave = tid >> 6, lane = tid & 63;
  const int wr = wave >> 2, wc = wave & 3;

  const int nwg = gridDim.x, cpx = nwg >> 3, bid = blockIdx.x;
  const int wg = (bid & 7) * cpx + (bid >> 3);
  const int nbn = N / 128;
  const int m0 = (wg / nbn) * 256, n0 = (wg % nbn) * 128;

  const int scol = 8 * ((tid & 7) ^ ((tid >> 3) & 7));
  const int wo = wave * 512;

  const ushort_t* aStgLo = A + (size_t)(m0 + (tid >> 3)) * K + scol;
  const ushort_t* aStgHi = aStgLo + (size_t)128 * K;
  const ushort_t* bStg   = B + (size_t)(n0 + (tid >> 3)) * K + scol;

  f32x4 acc[4][2] = {};

  {
    ushort_t* s0p = lds;
    gl2lds16(aStgLo, s0p + wo);
    gl2lds16(aStgHi, s0p + 8192 + wo);
    gl2lds16(bStg,   s0p + TILEA + wo);
    ushort_t* s1p = lds + SLOT;
    gl2lds16(aStgLo + 64, s1p + wo);
    gl2lds16(aStgHi + 64, s1p + 8192 + wo);
    gl2lds16(bStg   + 64, s1p + TILEA + wo);
    aStgLo += 128; aStgHi += 128; bStg += 128;
  }
  fence_vm<3>(); bar();

  const int rl = lane & 15, c4 = lane >> 4;
  const int sw0 = (c4 ^ (rl & 7)) * 8;
  const int sw1 = ((4 | c4) ^ (rl & 7)) * 8;
  const int aOff = (wr * 64 + rl) * 64;
  const int bOff = TILEA + (wc * 32 + rl) * 64;

  const ushort_t* rSlot = lds;
  ushort_t*       wSlot = lds + 2 * SLOT;

  for (int t = 0; t < NT; ++t) {
    const ushort_t* ra0 = rSlot + aOff + sw0;
    const ushort_t* ra1 = rSlot + aOff + sw1;
    const ushort_t* rb0 = rSlot + bOff + sw0;
    const ushort_t* rb1 = rSlot + bOff + sw1;

    short8 af[2][4], bf[2][2];
    #pragma unroll
    for (int m = 0; m < 4; m++) {
      af[0][m] = *(const short8*)(ra0 + m * 1024);
      af[1][m] = *(const short8*)(ra1 + m * 1024);
    }
    #pragma unroll
    for (int n = 0; n < 2; n++) {
      bf[0][n] = *(const short8*)(rb0 + n * 1024);
      bf[1][n] = *(const short8*)(rb1 + n * 1024);
    }

    if (t + 2 < NT) {
      gl2lds16(aStgLo, wSlot + wo);
      gl2lds16(aStgHi, wSlot + 8192 + wo);
      gl2lds16(bStg,   wSlot + TILEA + wo);
      aStgLo += 64; aStgHi += 64; bStg += 64;
    }

    __builtin_amdgcn_s_setprio(1);
    #pragma unroll
    for (int kk = 0; kk < 2; kk++)
      #pragma unroll
      for (int m = 0; m < 4; m++)
        #pragma unroll
        for (int n = 0; n < 2; n++)
          acc[m][n] = __builtin_amdgcn_mfma_f32_16x16x32_bf16(af[kk][m], bf[kk][n],
                                                              acc[m][n], 0, 0, 0);
    __builtin_amdgcn_s_setprio(0);

    if (t + 2 < NT) fence_vm<3>();
    else            fence_vm<0>();
    bar();

    const ushort_t* rn = rSlot + SLOT;
    rSlot = (rn == lds + 3 * SLOT) ? lds : rn;
    ushort_t* wn = wSlot + SLOT;
    wSlot = (wn == lds + 3 * SLOT) ? lds : wn;
  }

  const int colb = n0 + wc * 32 + rl;
  const int rowb = m0 + wr * 64 + c4 * 4;
  #pragma unroll
  for (int n = 0; n < 2; n++) {
    int col = colb + n * 16;
    float bs = bias[col];
    #pragma unroll
    for (int m = 0; m < 4; m++) {
      int row = rowb + m * 16;
      #pragma unroll
      for (int j = 0; j < 4; j++) {
        float v = acc[m][n][j] + bs;
        size_t o = (size_t)(row + j) * N + col;
        if (MODE == 1) {
          float g = v / (1.f + __expf(-1.702f * v));
          ((ushort_t*)outp)[o] = f2bf(g);
        } else {
          ((float*)outp)[o] = resid[o] + v;
        }
      }
    }
  }
}

// ---------------- launch ----------------
extern "C" void kernel_launch(void* const* d_in, const int* in_sizes, int n_in,
                              void* d_out, int out_size, void* d_ws, size_t ws_size,
                              hipStream_t stream) {
  (void)in_sizes; (void)n_in; (void)out_size; (void)ws_size;
  const float* x      = (const float*)d_in[0];
  const float* A_ssm  = (const float*)d_in[1];
  const float* B_ssm  = (const float*)d_in[2];
  const float* C_ssm  = (const float*)d_in[3];
  const float* D_ssm  = (const float*)d_in[4];
  const float* scale1 = (const float*)d_in[5];
  const float* scale2 = (const float*)d_in[6];
  const float* w1     = (const float*)d_in[7];
  const float* b1     = (const float*)d_in[8];
  const float* w2     = (const float*)d_in[9];
  const float* b2     = (const float*)d_in[10];
  float* out = (float*)d_out;

  char* ws = (char*)d_ws;
  float*    rrms  = (float*)(ws + 0);                         // 32 KB
  float*    dA_t  = (float*)(ws + 32768);                     // 64 KB
  float*    dBz_t = (float*)(ws + 98304);                     // 64 KB
  float*    dAc_t = (float*)(ws + 163840);                    // 64 KB
  float*    Ct    = (float*)(ws + 229376);                    // 64 KB
  float*    s_fin = (float*)(ws + 294912);                    // 8 MB
  float*    s_in  = (float*)(ws + 8683520);                   // 8 MB
  ushort_t* hb    = (ushort_t*)(ws + 17072128);               // 16 MB
  ushort_t* w1t   = (ushort_t*)(ws + 33849344);               // 8 MB
  ushort_t* w2t   = (ushort_t*)(ws + 42237952);               // 8 MB
  ushort_t* gb    = (ushort_t*)(ws + 50626560);               // 64 MB

  const int ROWS = BATCH * SEQLEN;  // 8192

  coef_kernel<<<DMODEL / 256, 256, 0, stream>>>(A_ssm, B_ssm, C_ssm, dA_t, dBz_t, dAc_t, Ct);
  transpose_to_bf16<<<dim3(DFF / 32, DMODEL / 32), dim3(32, 8), 0, stream>>>(w1, w1t, DMODEL, DFF);
  transpose_to_bf16<<<dim3(DMODEL / 32, DFF / 32), dim3(32, 8), 0, stream>>>(w2, w2t, DFF, DMODEL);
  rms1_kernel<<<ROWS / 4, 256, 0, stream>>>(x, rrms);
  scan_pass1<<<dim3(DMODEL / 256, BATCH, NCH), 256, 0, stream>>>(x, rrms, scale1, dA_t, dBz_t, s_fin);
  scan_pass2<<<(BATCH * DMODEL * NSTATE) / 256, 256, 0, stream>>>(s_fin, dAc_t, s_in);
  scan_pass3<<<dim3(DMODEL / 256, BATCH, NCH), 256, 0, stream>>>(x, rrms, scale1, dA_t, dBz_t, Ct,
                                                                 D_ssm, s_in, out);
  rms2_kernel<<<ROWS / 4, 256, 0, stream>>>(out, scale2, hb);

  // gemm1: [8192x1024]@[1024x4096] -> gelu -> gb (bf16). 512 blocks, 256x256, 8-phase.
  gemm8f<DMODEL><<<(ROWS / 256) * (DFF / 256), 512, 0, stream>>>(
      hb, w1t, b1, gb, ROWS, DFF);
  // gemm2: [8192x4096]@[4096x1024] + resid -> out (f32). 256 blocks, 256x128, BK=64.
  gemm16v<DFF, 2><<<(ROWS / 256) * (DMODEL / 128), 1024, 0, stream>>>(
      gb, w2t, b2, out, out, ROWS, DMODEL);
}